// Round 1
// baseline (740.117 us; speedup 1.0000x reference)
//
#include <hip/hip_runtime.h>

typedef _Float16 half8 __attribute__((ext_vector_type(8)));
typedef _Float16 half4 __attribute__((ext_vector_type(4)));
typedef float    f32x4 __attribute__((ext_vector_type(4)));

#define MFMA32(a,b,c) __builtin_amdgcn_mfma_f32_16x16x32_f16(a,b,c,0,0,0)
#define MFMA16(a,b,c) __builtin_amdgcn_mfma_f32_16x16x16f16(a,b,c,0,0,0)

#if __has_builtin(__builtin_amdgcn_exp2f)
#define EXP2F(x) __builtin_amdgcn_exp2f(x)
#else
#define EXP2F(x) exp2f(x)
#endif

// scale = DH^-0.5 = 1/8, folded together with log2(e) into Q so softmax uses exp2.
static constexpr float SCALE_LOG2E = 0.18033688011112042f;

// ---------------------------------------------------------------------------
// K1: qkv projection. C[8192,1536] = X[8192,512] @ W[512,1536] + b.
// Scatters to Qh[b][h][n][64] (xSCALE_LOG2E), Kh[b][h][n][64], Vt[b][h][64][n], all f16.
// ---------------------------------------------------------------------------
__global__ __launch_bounds__(256)
void k_qkv(const float* __restrict__ x, const float* __restrict__ w,
           const float* __restrict__ bias, _Float16* __restrict__ Qh,
           _Float16* __restrict__ Kh, _Float16* __restrict__ Vt)
{
  __shared__ __align__(16) _Float16 Xs[64*40];   // 64 rows x 32 k (+8 pad)
  __shared__ __align__(16) _Float16 Wt[64*40];   // 64 cols x 32 k (transposed, +8 pad)
  const int tid = threadIdx.x;
  const int wv = tid >> 6, lane = tid & 63, l15 = lane & 15, qd = lane >> 4;
  const int row0 = blockIdx.y * 64, col0 = blockIdx.x * 64;

  const int xr = tid >> 2, xc = (tid & 3) * 8;
  const int wk = tid >> 3, wc = (tid & 7) * 8;

  f32x4 acc[4] = {{0.f,0.f,0.f,0.f},{0.f,0.f,0.f,0.f},{0.f,0.f,0.f,0.f},{0.f,0.f,0.f,0.f}};

  for (int k0 = 0; k0 < 512; k0 += 32) {
    f32x4 a0 = *(const f32x4*)(x + (size_t)(row0 + xr) * 512 + k0 + xc);
    f32x4 a1 = *(const f32x4*)(x + (size_t)(row0 + xr) * 512 + k0 + xc + 4);
    f32x4 b0 = *(const f32x4*)(w + (size_t)(k0 + wk) * 1536 + col0 + wc);
    f32x4 b1 = *(const f32x4*)(w + (size_t)(k0 + wk) * 1536 + col0 + wc + 4);
    half8 hx;
#pragma unroll
    for (int j = 0; j < 4; j++) { hx[j] = (_Float16)a0[j]; hx[j+4] = (_Float16)a1[j]; }
    *(half8*)&Xs[xr*40 + xc] = hx;
#pragma unroll
    for (int j = 0; j < 4; j++) {
      Wt[(wc+j  )*40 + wk] = (_Float16)b0[j];
      Wt[(wc+j+4)*40 + wk] = (_Float16)b1[j];
    }
    __syncthreads();
    half8 af = *(const half8*)&Xs[(wv*16 + l15)*40 + qd*8];
#pragma unroll
    for (int ct = 0; ct < 4; ct++) {
      half8 bf = *(const half8*)&Wt[(ct*16 + l15)*40 + qd*8];
      acc[ct] = MFMA32(af, bf, acc[ct]);
    }
    __syncthreads();
  }
#pragma unroll
  for (int ct = 0; ct < 4; ct++) {
    const int c = col0 + ct*16 + l15;
    const int sec = c >> 9, hh = (c >> 6) & 7, d = c & 63;
    const float bv = bias[c];
#pragma unroll
    for (int i = 0; i < 4; i++) {
      const int row = row0 + wv*16 + qd*4 + i;
      const int bb = row >> 11, n = row & 2047;
      float v = acc[ct][i] + bv;
      if (sec == 0)
        Qh[((size_t)((bb*8 + hh)*2048 + n))*64 + d] = (_Float16)(v * SCALE_LOG2E);
      else if (sec == 1)
        Kh[((size_t)((bb*8 + hh)*2048 + n))*64 + d] = (_Float16)v;
      else
        Vt[((size_t)((bb*8 + hh)*64 + d))*2048 + n] = (_Float16)v;
    }
  }
}

// ---------------------------------------------------------------------------
// K2: pass 1 — softmax denominators. l[b,g,n] = sum_m exp2(sum_h th1[g,h]*S_h[n,m]).
// No max-subtraction (logits are tiny: |S'| < ~2). Writes Linv = 1/l.
// Grid 256 = 4b x 64 n-tiles(32). Block: 4 waves; waves pair on 16 rows, parity
// splits the 8 output heads g (each wave mixes/accumulates 4 g).
// ---------------------------------------------------------------------------
__global__ __launch_bounds__(256, 1)
void k_pass1(const _Float16* __restrict__ Qh, const _Float16* __restrict__ Kh,
             const float* __restrict__ th1, float* __restrict__ Linv)
{
  __shared__ __align__(16) _Float16 Ks[8*32*72];  // 8h x 32m x 64d(+8 pad)
  const int tid = threadIdx.x;
  const int wv = tid >> 6, lane = tid & 63, l15 = lane & 15, qd = lane >> 4;
  const int b = blockIdx.x >> 6, nt = blockIdx.x & 63;
  const int n0 = nt*32 + (wv >> 1)*16;
  const int p = wv & 1;

  float t1[4][8];
#pragma unroll
  for (int gg = 0; gg < 4; gg++)
#pragma unroll
    for (int h = 0; h < 8; h++)
      t1[gg][h] = th1[(p*4 + gg)*8 + h];

  half8 qf[8][2];
#pragma unroll
  for (int h = 0; h < 8; h++)
#pragma unroll
    for (int kc = 0; kc < 2; kc++)
      qf[h][kc] = *(const half8*)(Qh + ((size_t)((b*8 + h)*2048 + n0 + l15))*64 + kc*32 + qd*8);

  f32x4 lsum[4] = {{0.f,0.f,0.f,0.f},{0.f,0.f,0.f,0.f},{0.f,0.f,0.f,0.f},{0.f,0.f,0.f,0.f}};

  const int sh = tid >> 5, sm = tid & 31;
  const _Float16* ksrc0 = Kh + ((size_t)((b*8 + sh)*2048 + sm))*64;
  _Float16* kdst = &Ks[(sh*32 + sm)*72];

  for (int m0 = 0; m0 < 2048; m0 += 32) {
    const _Float16* s = ksrc0 + (size_t)m0*64;
#pragma unroll
    for (int j = 0; j < 8; j++)
      *(half8*)(kdst + j*8) = *(const half8*)(s + j*8);
    __syncthreads();
#pragma unroll
    for (int mc = 0; mc < 2; mc++) {
      f32x4 sp[4] = {{0.f,0.f,0.f,0.f},{0.f,0.f,0.f,0.f},{0.f,0.f,0.f,0.f},{0.f,0.f,0.f,0.f}};
#pragma unroll
      for (int h = 0; h < 8; h++) {
        const _Float16* kb = &Ks[(h*32 + mc*16 + l15)*72 + qd*8];
        half8 kb0 = *(const half8*)kb;
        half8 kb1 = *(const half8*)(kb + 32);
        f32x4 s4 = {0.f,0.f,0.f,0.f};
        s4 = MFMA32(qf[h][0], kb0, s4);
        s4 = MFMA32(qf[h][1], kb1, s4);
#pragma unroll
        for (int gg = 0; gg < 4; gg++)
#pragma unroll
          for (int i = 0; i < 4; i++)
            sp[gg][i] += t1[gg][h] * s4[i];
      }
#pragma unroll
      for (int gg = 0; gg < 4; gg++)
#pragma unroll
        for (int i = 0; i < 4; i++)
          lsum[gg][i] += EXP2F(sp[gg][i]);
    }
    __syncthreads();
  }

#pragma unroll
  for (int gg = 0; gg < 4; gg++)
#pragma unroll
    for (int i = 0; i < 4; i++) {
      float v = lsum[gg][i];
      v += __shfl_xor(v, 1);
      v += __shfl_xor(v, 2);
      v += __shfl_xor(v, 4);
      v += __shfl_xor(v, 8);
      if (l15 == 0)
        Linv[(size_t)(b*8 + p*4 + gg)*2048 + n0 + qd*4 + i] = 1.0f / v;
    }
}

// ---------------------------------------------------------------------------
// K3: pass 2 — recompute scores, normalize with Linv, th2-mix, PV, write O.
// Per 16-m chunk: scores (MFMA 16x16x32) -> th1 mix (VALU) -> exp2*invl ->
// th2 mix (VALU) -> W via LDS (C-layout -> A-layout) -> PV (MFMA 16x16x16).
// ---------------------------------------------------------------------------
__global__ __launch_bounds__(256, 1)
void k_pass2(const _Float16* __restrict__ Qh, const _Float16* __restrict__ Kh,
             const _Float16* __restrict__ Vt, const float* __restrict__ Linv,
             const float* __restrict__ th1, const float* __restrict__ th2,
             _Float16* __restrict__ Obuf)
{
  __shared__ __align__(16) _Float16 Ks[8*16*72];   // 18432 B
  __shared__ __align__(16) _Float16 Vs[8*64*20];   // 20480 B : [g][d][16m +4 pad]
  __shared__ __align__(16) _Float16 Wl[16*16*20];  // 10240 B : [wv*4+gg][16n][16m +4 pad]
  const int tid = threadIdx.x;
  const int wv = tid >> 6, lane = tid & 63, l15 = lane & 15, qd = lane >> 4;
  const int b = blockIdx.x >> 6, nt = blockIdx.x & 63;
  const int n0 = nt*32 + (wv >> 1)*16;
  const int p = wv & 1;

  float t1[8][8];
#pragma unroll
  for (int g = 0; g < 8; g++)
#pragma unroll
    for (int h = 0; h < 8; h++)
      t1[g][h] = th1[g*8 + h];
  float t2[4][8];
#pragma unroll
  for (int gg = 0; gg < 4; gg++)
#pragma unroll
    for (int g = 0; g < 8; g++)
      t2[gg][g] = th2[(p*4 + gg)*8 + g];
  float invl[8][4];
#pragma unroll
  for (int h = 0; h < 8; h++)
#pragma unroll
    for (int i = 0; i < 4; i++)
      invl[h][i] = Linv[(size_t)(b*8 + h)*2048 + n0 + qd*4 + i];

  half8 qf[8][2];
#pragma unroll
  for (int h = 0; h < 8; h++)
#pragma unroll
    for (int kc = 0; kc < 2; kc++)
      qf[h][kc] = *(const half8*)(Qh + ((size_t)((b*8 + h)*2048 + n0 + l15))*64 + kc*32 + qd*8);

  f32x4 og[4][4];
#pragma unroll
  for (int gg = 0; gg < 4; gg++)
#pragma unroll
    for (int dt = 0; dt < 4; dt++)
      og[gg][dt] = (f32x4){0.f,0.f,0.f,0.f};

  const int krow = tid >> 1, khalf = tid & 1;       // 128 K rows, split in 2 halves
  const int kh_ = krow >> 4, km_ = krow & 15;
  const _Float16* ksrc0 = Kh + ((size_t)((b*8 + kh_)*2048 + km_))*64 + khalf*32;
  _Float16* kdst = &Ks[(kh_*16 + km_)*72 + khalf*32];
  const _Float16* vbase = Vt + (size_t)(b*8)*64*2048;

  for (int m0 = 0; m0 < 2048; m0 += 16) {
    { // stage K tile: 8h x 16m x 64d
      const _Float16* s = ksrc0 + (size_t)m0*64;
#pragma unroll
      for (int j = 0; j < 4; j++)
        *(half8*)(kdst + j*8) = *(const half8*)(s + j*8);
    }
#pragma unroll
    for (int rr = 0; rr < 2; rr++) { // stage V tile: 512 (g,d) rows x 16m
      const int row = tid*2 + rr;
      const _Float16* s = vbase + (size_t)row*2048 + m0;
      half8 v8a = *(const half8*)s;
      half8 v8b = *(const half8*)(s + 8);
      _Float16* d = &Vs[row*20];
      *(half4*)(d)      = __builtin_shufflevector(v8a, v8a, 0,1,2,3);
      *(half4*)(d + 4)  = __builtin_shufflevector(v8a, v8a, 4,5,6,7);
      *(half4*)(d + 8)  = __builtin_shufflevector(v8b, v8b, 0,1,2,3);
      *(half4*)(d + 12) = __builtin_shufflevector(v8b, v8b, 4,5,6,7);
    }
    __syncthreads();

    // scores for all 8 softmax heads, th1-mixed
    f32x4 sp[8];
#pragma unroll
    for (int g = 0; g < 8; g++) sp[g] = (f32x4){0.f,0.f,0.f,0.f};
#pragma unroll
    for (int h = 0; h < 8; h++) {
      const _Float16* kb = &Ks[(h*16 + l15)*72 + qd*8];
      half8 kb0 = *(const half8*)kb;
      half8 kb1 = *(const half8*)(kb + 32);
      f32x4 s4 = {0.f,0.f,0.f,0.f};
      s4 = MFMA32(qf[h][0], kb0, s4);
      s4 = MFMA32(qf[h][1], kb1, s4);
#pragma unroll
      for (int g = 0; g < 8; g++)
#pragma unroll
        for (int i = 0; i < 4; i++)
          sp[g][i] += t1[g][h] * s4[i];
    }
    // softmax weights (normalized by precomputed 1/l), th2 mix
    f32x4 wacc[4];
#pragma unroll
    for (int gg = 0; gg < 4; gg++) wacc[gg] = (f32x4){0.f,0.f,0.f,0.f};
#pragma unroll
    for (int g = 0; g < 8; g++) {
      f32x4 pr;
#pragma unroll
      for (int i = 0; i < 4; i++)
        pr[i] = EXP2F(sp[g][i]) * invl[g][i];
#pragma unroll
      for (int gg = 0; gg < 4; gg++)
#pragma unroll
        for (int i = 0; i < 4; i++)
          wacc[gg][i] += t2[gg][g] * pr[i];
    }
    // C-layout -> A-layout via LDS (wave-private region; in-wave lgkm ordering)
#pragma unroll
    for (int gg = 0; gg < 4; gg++)
#pragma unroll
      for (int i = 0; i < 4; i++)
        Wl[((wv*4 + gg)*16 + qd*4 + i)*20 + l15] = (_Float16)wacc[gg][i];

    // PV: og[gg][dt] += W[16n x 16m] * V[16m x 16d]
#pragma unroll
    for (int gg = 0; gg < 4; gg++) {
      half4 af = *(const half4*)&Wl[((wv*4 + gg)*16 + l15)*20 + qd*4];
      const int gp = p*4 + gg;
#pragma unroll
      for (int dt = 0; dt < 4; dt++) {
        half4 bf = *(const half4*)&Vs[(gp*64 + dt*16 + l15)*20 + qd*4];
        og[gg][dt] = MFMA16(af, bf, og[gg][dt]);
      }
    }
    __syncthreads();
  }

#pragma unroll
  for (int gg = 0; gg < 4; gg++)
#pragma unroll
    for (int dt = 0; dt < 4; dt++)
#pragma unroll
      for (int i = 0; i < 4; i++) {
        const int col = (p*4 + gg)*64 + dt*16 + l15;
        const int n = n0 + qd*4 + i;
        Obuf[((size_t)(b*2048 + n))*512 + col] = (_Float16)og[gg][dt][i];
      }
}

// ---------------------------------------------------------------------------
// K4: output projection. out[8192,512] = Obuf[8192,512] @ w_out[512,512] + b_out (fp32 out)
// ---------------------------------------------------------------------------
__global__ __launch_bounds__(256)
void k_oproj(const _Float16* __restrict__ A, const float* __restrict__ w,
             const float* __restrict__ bias, float* __restrict__ out)
{
  __shared__ __align__(16) _Float16 Xs[64*40];
  __shared__ __align__(16) _Float16 Wt[64*40];
  const int tid = threadIdx.x;
  const int wv = tid >> 6, lane = tid & 63, l15 = lane & 15, qd = lane >> 4;
  const int row0 = blockIdx.y * 64, col0 = blockIdx.x * 64;
  const int xr = tid >> 2, xc = (tid & 3) * 8;
  const int wk = tid >> 3, wc = (tid & 7) * 8;

  f32x4 acc[4] = {{0.f,0.f,0.f,0.f},{0.f,0.f,0.f,0.f},{0.f,0.f,0.f,0.f},{0.f,0.f,0.f,0.f}};

  for (int k0 = 0; k0 < 512; k0 += 32) {
    *(half8*)&Xs[xr*40 + xc] = *(const half8*)(A + (size_t)(row0 + xr)*512 + k0 + xc);
    f32x4 b0 = *(const f32x4*)(w + (size_t)(k0 + wk)*512 + col0 + wc);
    f32x4 b1 = *(const f32x4*)(w + (size_t)(k0 + wk)*512 + col0 + wc + 4);
#pragma unroll
    for (int j = 0; j < 4; j++) {
      Wt[(wc+j  )*40 + wk] = (_Float16)b0[j];
      Wt[(wc+j+4)*40 + wk] = (_Float16)b1[j];
    }
    __syncthreads();
    half8 af = *(const half8*)&Xs[(wv*16 + l15)*40 + qd*8];
#pragma unroll
    for (int ct = 0; ct < 4; ct++) {
      half8 bf = *(const half8*)&Wt[(ct*16 + l15)*40 + qd*8];
      acc[ct] = MFMA32(af, bf, acc[ct]);
    }
    __syncthreads();
  }
#pragma unroll
  for (int ct = 0; ct < 4; ct++) {
    const int c = col0 + ct*16 + l15;
    const float bv = bias[c];
#pragma unroll
    for (int i = 0; i < 4; i++) {
      const int row = row0 + wv*16 + qd*4 + i;
      out[(size_t)row*512 + c] = acc[ct][i] + bv;
    }
  }
}

// ---------------------------------------------------------------------------
extern "C" void kernel_launch(void* const* d_in, const int* in_sizes, int n_in,
                              void* d_out, int out_size, void* d_ws, size_t ws_size,
                              hipStream_t stream)
{
  (void)in_sizes; (void)n_in; (void)out_size;
  const float* x     = (const float*)d_in[0];
  const float* w_qkv = (const float*)d_in[1];
  const float* b_qkv = (const float*)d_in[2];
  const float* th1   = (const float*)d_in[3];
  const float* th2   = (const float*)d_in[4];
  const float* w_out = (const float*)d_in[5];
  const float* b_out = (const float*)d_in[6];
  float* out = (float*)d_out;

  char* ws = (char*)d_ws;
  _Float16* Qh   = (_Float16*)(ws);
  _Float16* Kh   = (_Float16*)(ws + ((size_t)8  << 20));
  _Float16* Vt   = (_Float16*)(ws + ((size_t)16 << 20));
  float*    Linv = (float*)   (ws + ((size_t)24 << 20));
  _Float16* Obuf = (_Float16*)(ws + ((size_t)25 << 20));
  if (ws_size < ((size_t)33 << 20)) return;  // need 33 MB scratch

  k_qkv  <<<dim3(24, 128), 256, 0, stream>>>(x, w_qkv, b_qkv, Qh, Kh, Vt);
  k_pass1<<<dim3(256),     256, 0, stream>>>(Qh, Kh, th1, Linv);
  k_pass2<<<dim3(256),     256, 0, stream>>>(Qh, Kh, Vt, Linv, th1, th2, Obuf);
  k_oproj<<<dim3(8, 128),  256, 0, stream>>>(Obuf, w_out, b_out, out);
}